// Round 5
// baseline (80.877 us; speedup 1.0000x reference)
//
#include <hip/hip_runtime.h>
#include <hip/hip_bf16.h>

#define NB 4096

typedef short v8s __attribute__((ext_vector_type(8)));
typedef float v4f __attribute__((ext_vector_type(4)));

// ws layout: part[4096*32] float2 (1 MB) | sq[4096] f32 (16 KB) | xbT bf16 k-chunk-major (1 MB)
// xbT element layout: chunk c = k/8 (0..15): xbT[(c*4096 + row)*8 + (k%8)]

__device__ __forceinline__ void dma16(const unsigned short* g, unsigned short* l) {
    __builtin_amdgcn_global_load_lds(
        (const __attribute__((address_space(1))) unsigned int*)g,
        (__attribute__((address_space(3))) unsigned int*)l, 16, 0, 0);
}

__global__ __launch_bounds__(256) void prep_kernel(const float* __restrict__ x,
        float* __restrict__ sq, unsigned short* __restrict__ xbT,
        float* __restrict__ out) {
    int tid = threadIdx.x;
    int row = blockIdx.x * 8 + (tid >> 5);
    int lane = tid & 31;
    const float4* xg = (const float4*)x;
    float4 v = xg[row * 32 + lane];            // k = 4*lane .. 4*lane+3
    __hip_bfloat16 h0 = __float2bfloat16(v.x), h1 = __float2bfloat16(v.y);
    __hip_bfloat16 h2 = __float2bfloat16(v.z), h3 = __float2bfloat16(v.w);
    ushort4 u4;
    u4.x = *(unsigned short*)&h0; u4.y = *(unsigned short*)&h1;
    u4.z = *(unsigned short*)&h2; u4.w = *(unsigned short*)&h3;
    int c = lane >> 1, half = lane & 1;        // 8-wide chunk, which 4 of it
    *(ushort4*)&xbT[((size_t)c * 4096 + row) * 8 + half * 4] = u4;
    // sq from bf16-rounded values (consistent with MFMA dot -> diag dist == 0)
    float f0 = __bfloat162float(h0), f1 = __bfloat162float(h1);
    float f2 = __bfloat162float(h2), f3 = __bfloat162float(h3);
    float s = f0 * f0 + f1 * f1 + f2 * f2 + f3 * f3;
    #pragma unroll
    for (int off = 16; off > 0; off >>= 1) s += __shfl_down(s, off);
    if (lane == 0) sq[row] = s;
    if (blockIdx.x == 0 && tid == 0) out[0] = 0.f;
}

// Triangular grid (bx<=by), 128x128 tile per block. Double-buffered 8KB k-slabs
// staged via global_load_lds; 4 blocks/CU target.
__global__ __launch_bounds__(256, 4) void snn_mfma(const unsigned short* __restrict__ xbT,
        const int* __restrict__ y, const float* __restrict__ sqg,
        float2* __restrict__ part) {
    // slab[buf][tile(A/B)][q][row][8 bf16]: 16B chunk = A[row][k=kk*32+q*8..+8]
    // frag ds_read_b128: lanes stride 16B -> 2-way bank alias = free.
    // red[] (4KB) overlays buf0: last K-iter (kk=3) reads buf1 only -> safe.
    __shared__ __align__(16) union {
        unsigned short slab[2][2][4][128][8];   // 32768 B
        float2 red[4][128];                     // [wn rowN/D | wm colN/D]
    } sm;
    __shared__ float sqi[128], sqj[128];
    __shared__ int yi[128], yj[128];

    const int tid = threadIdx.x;
    const int w    = tid >> 6;     // wave 0..3
    const int lane = tid & 63;
    const int wm = w >> 1;
    const int wn = w & 1;
    const int lr = lane & 15;
    const int q  = lane >> 4;

    int t = blockIdx.x;            // triangular decode: t = by*(by+1)/2 + bx
    int by = (int)((sqrtf(8.0f * (float)t + 1.0f) - 1.0f) * 0.5f);
    if (by * (by + 1) / 2 > t) --by;
    if ((by + 1) * (by + 2) / 2 <= t) ++by;
    int bx = t - by * (by + 1) / 2;
    const int i0 = bx * 128;
    const int j0 = by * 128;
    const bool offdiag = (bx != by);

    // stage slabs for kk into buf: wave w covers q=w, rows lane (h=0) / 64+lane (h=1)
    #define STAGE(buf, kk) do {                                                  \
        int c_ = (kk) * 4 + w;                                                   \
        const unsigned short* gA_ = xbT + ((size_t)(c_ * 4096 + i0) + lane) * 8; \
        const unsigned short* gB_ = xbT + ((size_t)(c_ * 4096 + j0) + lane) * 8; \
        unsigned short* lA_ = &sm.slab[buf][0][w][0][0];                         \
        unsigned short* lB_ = &sm.slab[buf][1][w][0][0];                         \
        dma16(gA_,          lA_);                                                \
        dma16(gA_ + 64 * 8, lA_ + 64 * 8);                                       \
        dma16(gB_,          lB_);                                                \
        dma16(gB_ + 64 * 8, lB_ + 64 * 8);                                       \
    } while (0)

    STAGE(0, 0);
    if (tid < 128) { sqi[tid] = sqg[i0 + tid]; yi[tid] = y[i0 + tid]; }
    else { sqj[tid - 128] = sqg[j0 + tid - 128]; yj[tid - 128] = y[j0 + tid - 128]; }

    v4f acc[4][4];
    #pragma unroll
    for (int mt = 0; mt < 4; ++mt)
        #pragma unroll
        for (int nt = 0; nt < 4; ++nt)
            #pragma unroll
            for (int r = 0; r < 4; ++r) acc[mt][nt][r] = 0.f;

    #pragma unroll
    for (int kk = 0; kk < 4; ++kk) {
        __syncthreads();   // drains own DMAs (vmcnt) + publishes slabs for kk
        const int buf = kk & 1;
        v8s af[4], bf[4];
        #pragma unroll
        for (int mt = 0; mt < 4; ++mt)
            af[mt] = *(const v8s*)&sm.slab[buf][0][q][wm * 64 + mt * 16 + lr][0];
        #pragma unroll
        for (int nt = 0; nt < 4; ++nt)
            bf[nt] = *(const v8s*)&sm.slab[buf][1][q][wn * 64 + nt * 16 + lr][0];
        if (kk < 3) STAGE(buf ^ 1, kk + 1);   // overlap kk+1 DMAs with kk MFMAs
        #pragma unroll
        for (int mt = 0; mt < 4; ++mt)
            #pragma unroll
            for (int nt = 0; nt < 4; ++nt)
                acc[mt][nt] = __builtin_amdgcn_mfma_f32_16x16x32_bf16(
                    af[mt], bf[nt], acc[mt][nt], 0, 0, 0);
    }

    // epilogue: dist -> exp -> masked num/den; in-wave quad butterflies for rows
    float sqj_r[4]; int yj_r[4], jg[4];
    #pragma unroll
    for (int nt = 0; nt < 4; ++nt) {
        int jc = wn * 64 + nt * 16 + lr;
        sqj_r[nt] = sqj[jc]; yj_r[nt] = yj[jc]; jg[nt] = j0 + jc;
    }
    float colN[4] = {0.f, 0.f, 0.f, 0.f};
    float colD[4] = {0.f, 0.f, 0.f, 0.f};

    #pragma unroll
    for (int mt = 0; mt < 4; ++mt) {
        #pragma unroll
        for (int r = 0; r < 4; ++r) {
            int rloc = wm * 64 + mt * 16 + q * 4 + r;   // C/D: row = q*4+reg
            float si = sqi[rloc]; int yir = yi[rloc]; int ig = i0 + rloc;
            float n = 0.f, d = 0.f;
            #pragma unroll
            for (int nt = 0; nt < 4; ++nt) {
                float dist = fmaxf(si + sqj_r[nt] - 2.f * acc[mt][nt][r], 0.f);
                float e = __builtin_amdgcn_exp2f(dist * -0.014426950408889634f);
                d += e;
                bool ok = (yir == yj_r[nt]) && (ig != jg[nt]);
                float ne = ok ? e : 0.f;
                n += ne;
                colN[nt] += ne;
                colD[nt] += e;
            }
            // reduce over the 16 col-lanes of the quad (masks <16 stay in-quad)
            n += __shfl_xor(n, 1); d += __shfl_xor(d, 1);
            n += __shfl_xor(n, 2); d += __shfl_xor(d, 2);
            n += __shfl_xor(n, 4); d += __shfl_xor(d, 4);
            n += __shfl_xor(n, 8); d += __shfl_xor(d, 8);
            if (lr == 0) sm.red[wn][rloc] = make_float2(n, d);   // red in buf0: free after kk=3
        }
    }
    if (offdiag) {   // symmetric contribution: reduce over the 4 quads
        #pragma unroll
        for (int nt = 0; nt < 4; ++nt) {
            float cn = colN[nt], cd = colD[nt];
            cn += __shfl_xor(cn, 16); cd += __shfl_xor(cd, 16);
            cn += __shfl_xor(cn, 32); cd += __shfl_xor(cd, 32);
            if (q == 0) sm.red[2 + wm][wn * 64 + nt * 16 + lr] = make_float2(cn, cd);
        }
    }
    __syncthreads();

    if (tid < 128) {
        float2 a = sm.red[0][tid], b = sm.red[1][tid];
        part[(i0 + tid) * 32 + by] = make_float2(a.x + b.x, a.y + b.y);
    } else if (offdiag) {
        int cc = tid - 128;
        float2 a = sm.red[2][cc], b = sm.red[3][cc];
        part[(j0 + cc) * 32 + bx] = make_float2(a.x + b.x, a.y + b.y);
    }
}

__global__ __launch_bounds__(256) void snn_final(const float2* __restrict__ part,
        float* __restrict__ out) {
    __shared__ float wsum[4];
    int row = blockIdx.x * 256 + threadIdx.x;
    const float4* p = (const float4*)&part[row * 32];
    float n = 0.f, d = 0.f;
    #pragma unroll
    for (int c = 0; c < 16; ++c) {
        float4 v = p[c];
        n += v.x + v.z; d += v.y + v.w;
    }
    float l = __logf(d) - __logf(n);
    #pragma unroll
    for (int off = 32; off > 0; off >>= 1) l += __shfl_down(l, off);
    int wid = threadIdx.x >> 6;
    if ((threadIdx.x & 63) == 0) wsum[wid] = l;
    __syncthreads();
    if (threadIdx.x == 0) {
        float s = wsum[0] + wsum[1] + wsum[2] + wsum[3];
        atomicAdd(out, s * (1.0f / NB));
    }
}

extern "C" void kernel_launch(void* const* d_in, const int* in_sizes, int n_in,
                              void* d_out, int out_size, void* d_ws, size_t ws_size,
                              hipStream_t stream) {
    const float* x = (const float*)d_in[0];
    const int*   y = (const int*)d_in[1];
    float* out = (float*)d_out;
    float2* part = (float2*)d_ws;
    float* sq = (float*)((char*)d_ws + (1 << 20));
    unsigned short* xbT = (unsigned short*)((char*)d_ws + (1 << 20) + (16 << 10));

    prep_kernel<<<NB / 8, 256, 0, stream>>>(x, sq, xbT, out);
    snn_mfma<<<528, 256, 0, stream>>>(xbT, y, sq, part);
    snn_final<<<NB / 256, 256, 0, stream>>>(part, out);
}

// Round 6
// 76.170 us; speedup vs baseline: 1.0618x; 1.0618x over previous
//
#include <hip/hip_runtime.h>
#include <hip/hip_bf16.h>

#define NB 4096

typedef short v8s __attribute__((ext_vector_type(8)));
typedef float v4f __attribute__((ext_vector_type(4)));

// ws layout: part[4096*32] float2 (1 MB) | sq[4096] f32 (16 KB) | xb[4096*128] bf16 row-major (1 MB)

__global__ __launch_bounds__(256) void prep_kernel(const float* __restrict__ x,
        float* __restrict__ sq, unsigned short* __restrict__ xb,
        float* __restrict__ out) {
    int tid = threadIdx.x;
    int row = blockIdx.x * 8 + (tid >> 5);
    int lane = tid & 31;
    const float4* xg = (const float4*)x;
    float4 v = xg[row * 32 + lane];
    __hip_bfloat16 h0 = __float2bfloat16(v.x), h1 = __float2bfloat16(v.y);
    __hip_bfloat16 h2 = __float2bfloat16(v.z), h3 = __float2bfloat16(v.w);
    ushort4 u4;
    u4.x = *(unsigned short*)&h0; u4.y = *(unsigned short*)&h1;
    u4.z = *(unsigned short*)&h2; u4.w = *(unsigned short*)&h3;
    ((ushort4*)xb)[row * 32 + lane] = u4;   // coalesced row-major
    // sq from bf16-rounded values (consistent with MFMA dot -> diag dist == 0)
    float f0 = __bfloat162float(h0), f1 = __bfloat162float(h1);
    float f2 = __bfloat162float(h2), f3 = __bfloat162float(h3);
    float s = f0 * f0 + f1 * f1 + f2 * f2 + f3 * f3;
    #pragma unroll
    for (int off = 16; off > 0; off >>= 1) s += __shfl_down(s, off);
    if (lane == 0) sq[row] = s;
    if (blockIdx.x == 0 && tid == 0) out[0] = 0.f;
}

// 512 threads / 8 waves per block; 128x128 tile; wave tile 32x64 (acc = 32 VGPR).
// Single-buffered K=128 LDS tiles, 2 barriers total, 4 waves/SIMD occupancy.
__global__ __launch_bounds__(512, 4) void snn_mfma(const unsigned short* __restrict__ xb,
        const int* __restrict__ y, const float* __restrict__ sqg,
        float2* __restrict__ part) {
    // stride 136 bf16 (68 dw): b128 frag reads hit the 8-dword/bank floor (no excess conflict)
    __shared__ __align__(16) unsigned short At[128 * 136];  // 34816 B
    __shared__ __align__(16) unsigned short Bt[128 * 136];  // 34816 B
    __shared__ float2 red[2][128];                          // 2048 B
    __shared__ float sqi[128], sqj[128];
    __shared__ int yi[128], yj[128];

    const int tid = threadIdx.x;
    const int w    = tid >> 6;     // 0..7
    const int lane = tid & 63;
    const int wm = w >> 1;         // 0..3 : 32-row band
    const int wn = w & 1;          // 0..1 : 64-col half
    const int lr = lane & 15;
    const int q  = lane >> 4;
    const int i0 = blockIdx.x * 128;
    const int j0 = blockIdx.y * 128;

    const v8s* xg = (const v8s*)xb;   // 16 chunks of 8 bf16 per row
    #pragma unroll
    for (int it = 0; it < 4; ++it) {
        int c = it * 512 + tid;
        int row = c >> 4, cc = c & 15;
        *(v8s*)&At[row * 136 + cc * 8] = xg[(i0 + row) * 16 + cc];
        *(v8s*)&Bt[row * 136 + cc * 8] = xg[(j0 + row) * 16 + cc];
    }
    if (tid < 128)      { sqi[tid] = sqg[i0 + tid];       yi[tid] = y[i0 + tid]; }
    else if (tid < 256) { sqj[tid - 128] = sqg[j0 + tid - 128];
                          yj[tid - 128] = y[j0 + tid - 128]; }
    __syncthreads();

    v4f acc[2][4];
    #pragma unroll
    for (int mt = 0; mt < 2; ++mt)
        #pragma unroll
        for (int nt = 0; nt < 4; ++nt)
            #pragma unroll
            for (int r = 0; r < 4; ++r) acc[mt][nt][r] = 0.f;

    #pragma unroll
    for (int kk = 0; kk < 4; ++kk) {
        v8s af[2], bf[4];
        #pragma unroll
        for (int mt = 0; mt < 2; ++mt)
            af[mt] = *(const v8s*)&At[(wm * 32 + mt * 16 + lr) * 136 + kk * 32 + q * 8];
        #pragma unroll
        for (int nt = 0; nt < 4; ++nt)
            bf[nt] = *(const v8s*)&Bt[(wn * 64 + nt * 16 + lr) * 136 + kk * 32 + q * 8];
        #pragma unroll
        for (int mt = 0; mt < 2; ++mt)
            #pragma unroll
            for (int nt = 0; nt < 4; ++nt)
                acc[mt][nt] = __builtin_amdgcn_mfma_f32_16x16x32_bf16(
                    af[mt], bf[nt], acc[mt][nt], 0, 0, 0);
    }

    // epilogue: e = exp2(min(0, 2c*acc - c*si - c*sj)); masked num, full den
    const float c1 = 0.014426950408889634f;   // log2(e)/100
    const float c2 = 0.028853900817778936f;   // 2*c1
    float bj[4]; int yj_r[4], jg[4];
    #pragma unroll
    for (int nt = 0; nt < 4; ++nt) {
        int jc = wn * 64 + nt * 16 + lr;
        bj[nt] = -c1 * sqj[jc]; yj_r[nt] = yj[jc]; jg[nt] = j0 + jc;
    }
    #pragma unroll
    for (int mt = 0; mt < 2; ++mt) {
        #pragma unroll
        for (int r = 0; r < 4; ++r) {
            int rloc = wm * 32 + mt * 16 + q * 4 + r;   // C/D: row = q*4+reg
            float bi = -c1 * sqi[rloc];
            int yir = yi[rloc], ig = i0 + rloc;
            float n = 0.f, d = 0.f;
            #pragma unroll
            for (int nt = 0; nt < 4; ++nt) {
                float arg = fminf(0.f, fmaf(acc[mt][nt][r], c2, bi + bj[nt]));
                float e = __builtin_amdgcn_exp2f(arg);
                d += e;
                bool ok = (yir == yj_r[nt]) && (ig != jg[nt]);
                n += ok ? e : 0.f;
            }
            // reduce over the 16 lr-lanes (same row, 64 cols); stays in-quad
            n += __shfl_xor(n, 1); d += __shfl_xor(d, 1);
            n += __shfl_xor(n, 2); d += __shfl_xor(d, 2);
            n += __shfl_xor(n, 4); d += __shfl_xor(d, 4);
            n += __shfl_xor(n, 8); d += __shfl_xor(d, 8);
            if (lr == 0) red[wn][rloc] = make_float2(n, d);
        }
    }
    __syncthreads();

    if (tid < 128) {
        float2 a = red[0][tid], b = red[1][tid];
        part[(i0 + tid) * 32 + blockIdx.y] = make_float2(a.x + b.x, a.y + b.y);
    }
}

__global__ __launch_bounds__(256) void snn_final(const float2* __restrict__ part,
        float* __restrict__ out) {
    __shared__ float wsum[4];
    int row = blockIdx.x * 256 + threadIdx.x;
    const float4* p = (const float4*)&part[row * 32];
    float n = 0.f, d = 0.f;
    #pragma unroll
    for (int c = 0; c < 16; ++c) {
        float4 v = p[c];
        n += v.x + v.z; d += v.y + v.w;
    }
    float l = __logf(d) - __logf(n);
    #pragma unroll
    for (int off = 32; off > 0; off >>= 1) l += __shfl_down(l, off);
    int wid = threadIdx.x >> 6;
    if ((threadIdx.x & 63) == 0) wsum[wid] = l;
    __syncthreads();
    if (threadIdx.x == 0) {
        float s = wsum[0] + wsum[1] + wsum[2] + wsum[3];
        atomicAdd(out, s * (1.0f / NB));
    }
}

extern "C" void kernel_launch(void* const* d_in, const int* in_sizes, int n_in,
                              void* d_out, int out_size, void* d_ws, size_t ws_size,
                              hipStream_t stream) {
    const float* x = (const float*)d_in[0];
    const int*   y = (const int*)d_in[1];
    float* out = (float*)d_out;
    float2* part = (float2*)d_ws;
    float* sq = (float*)((char*)d_ws + (1 << 20));
    unsigned short* xb = (unsigned short*)((char*)d_ws + (1 << 20) + (16 << 10));

    prep_kernel<<<NB / 8, 256, 0, stream>>>(x, sq, xb, out);
    dim3 grid(NB / 128, NB / 128);
    snn_mfma<<<grid, 512, 0, stream>>>(xb, y, sq, part);
    snn_final<<<NB / 256, 256, 0, stream>>>(part, out);
}